// Round 6
// baseline (405.627 us; speedup 1.0000x reference)
//
#include <hip/hip_runtime.h>
#include <math.h>

#define HIDDEN 1024
#define NSTATE 16
#define DTRANK 64
#define BB 2
#define SS 2048
#define ROWS (BB*SS)            // 4096
#define XPC 96                  // 2*STATE + DT_RANK
#define CH 64                   // chunks along S
#define CL 32                   // chunk length
#define BND (BB*NSTATE*HIDDEN)  // 32768
#define LOG2E 1.44269504088896f

#define RT 64                   // rows per xproj tile
#define KSPL 8                  // K splits in xproj
#define NBLK 512

// Manual grid barrier: per-phase counter, device-scope atomics (cross-XCD safe).
// Counters zeroed by hipMemsetAsync before each kernel launch.
__device__ __forceinline__ void gbar(int* c) {
    __syncthreads();
    if (threadIdx.x == 0) {
        __threadfence();                    // release: make this block's writes visible
        atomicAdd(c, 1);
        while (atomicAdd(c, 0) < NBLK)      // RMW poll: coherent across XCDs
            __builtin_amdgcn_s_sleep(2);
    }
    __syncthreads();
    __threadfence();                        // acquire: discard stale cached lines
}

__global__ __launch_bounds__(256, 2)
void k_fused(const float* __restrict__ x, const float* __restrict__ W,
             const float* __restrict__ Wdt, const float* __restrict__ bdt,
             const float* __restrict__ Alog,
             float* __restrict__ part, float* __restrict__ xp,
             float* __restrict__ dt, float* __restrict__ P,
             float* __restrict__ Q, float* __restrict__ y,
             int* __restrict__ bar) {
    __shared__ float smem[96 * 36 + RT * 32];   // 22KB: wt + xs
    float* wt = smem;
    float* xs = smem + 96 * 36;

    int t = threadIdx.x;
    int bidx = blockIdx.x;

    // ================= phase 1: xproj partials (K-split GEMM) =================
    {
        int rt = bidx >> 3;
        int ks = bidx & 7;
        int r0 = rt * RT;
        int k0 = ks * 128;
        int cg_ = t & 15, rg = t >> 4;

        float acc[4][6];
        #pragma unroll
        for (int a = 0; a < 4; ++a)
            #pragma unroll
            for (int b = 0; b < 6; ++b) acc[a][b] = 0.f;

        for (int ch = 0; ch < 4; ++ch) {
            int kc = k0 + ch * 32;
            __syncthreads();
            #pragma unroll
            for (int m = 0; m < 2; ++m) {
                int e = t + m * 256;
                int row = e >> 3, kb = e & 7;
                float4 v = *(const float4*)&x[(r0 + row) * HIDDEN + kc + kb * 4];
                int kbp = kb ^ ((row >> 2) & 7);
                *(float4*)&xs[row * 32 + kbp * 4] = v;
            }
            #pragma unroll
            for (int m = 0; m < 3; ++m) {
                int f = t + m * 256;
                int kr = f / 24, cq = f % 24;
                float4 v = *(const float4*)&W[(kc + kr) * XPC + cq * 4];
                wt[(cq * 4 + 0) * 36 + kr] = v.x;
                wt[(cq * 4 + 1) * 36 + kr] = v.y;
                wt[(cq * 4 + 2) * 36 + kr] = v.z;
                wt[(cq * 4 + 3) * 36 + kr] = v.w;
            }
            __syncthreads();
            #pragma unroll
            for (int kg = 0; kg < 8; ++kg) {
                float4 wv[6], xv[4];
                #pragma unroll
                for (int j = 0; j < 6; ++j)
                    wv[j] = *(float4*)&wt[(cg_ + 16 * j) * 36 + kg * 4];
                #pragma unroll
                for (int rr = 0; rr < 4; ++rr) {
                    int row = rg * 4 + rr;
                    xv[rr] = *(float4*)&xs[row * 32 + ((kg ^ ((row >> 2) & 7)) * 4)];
                }
                #pragma unroll
                for (int rr = 0; rr < 4; ++rr)
                    #pragma unroll
                    for (int j = 0; j < 6; ++j) {
                        acc[rr][j] = fmaf(xv[rr].x, wv[j].x, acc[rr][j]);
                        acc[rr][j] = fmaf(xv[rr].y, wv[j].y, acc[rr][j]);
                        acc[rr][j] = fmaf(xv[rr].z, wv[j].z, acc[rr][j]);
                        acc[rr][j] = fmaf(xv[rr].w, wv[j].w, acc[rr][j]);
                    }
            }
        }
        #pragma unroll
        for (int rr = 0; rr < 4; ++rr)
            #pragma unroll
            for (int j = 0; j < 6; ++j)
                part[ks * (ROWS * XPC) + (r0 + rg * 4 + rr) * XPC + cg_ + 16 * j] = acc[rr][j];
    }
    gbar(bar + 0);

    // ================= phase 2: reduce partials -> xp, dt GEMM + softplus =================
    {
        float* xs2 = smem;                 // 8*64 floats
        int r0 = bidx * 8;
        #pragma unroll
        for (int m = 0; m < 3; ++m) {
            int o = t + m * 256;           // 0..767
            int row = o / 96, col = o % 96;
            float s = 0.f;
            #pragma unroll
            for (int p = 0; p < KSPL; ++p)
                s += part[p * (ROWS * XPC) + (r0 + row) * XPC + col];
            xp[(r0 + row) * XPC + col] = s;
            if (col >= 2 * NSTATE) xs2[row * 64 + (col - 2 * NSTATE)] = s;
        }
        __syncthreads();
        float4 acc[8];
        float4 b = *(const float4*)&bdt[t * 4];
        #pragma unroll
        for (int rr = 0; rr < 8; ++rr) acc[rr] = b;
        #pragma unroll 4
        for (int k = 0; k < DTRANK; ++k) {
            float4 w = *(const float4*)&Wdt[k * HIDDEN + t * 4];
            #pragma unroll
            for (int rr = 0; rr < 8; ++rr) {
                float s = xs2[rr * 64 + k];
                acc[rr].x = fmaf(s, w.x, acc[rr].x);
                acc[rr].y = fmaf(s, w.y, acc[rr].y);
                acc[rr].z = fmaf(s, w.z, acc[rr].z);
                acc[rr].w = fmaf(s, w.w, acc[rr].w);
            }
        }
        #pragma unroll
        for (int rr = 0; rr < 8; ++rr) {
            float4 a = acc[rr], o;
            o.x = fmaxf(a.x, 0.f) + log1pf(__expf(-fabsf(a.x)));
            o.y = fmaxf(a.y, 0.f) + log1pf(__expf(-fabsf(a.y)));
            o.z = fmaxf(a.z, 0.f) + log1pf(__expf(-fabsf(a.z)));
            o.w = fmaxf(a.w, 0.f) + log1pf(__expf(-fabsf(a.w)));
            *(float4*)&dt[(r0 + rr) * HIDDEN + t * 4] = o;
        }
    }
    gbar(bar + 1);

    // ================= phase 3: per-chunk P=prod(a), Q=local scan end =================
    {
        int dblk = bidx & 3;
        int b = (bidx >> 2) & 1;
        int c = bidx >> 3;
        int d = dblk * 256 + t;
        float A2[NSTATE], Pv[NSTATE], Qv[NSTATE];
        #pragma unroll
        for (int n = 0; n < NSTATE; ++n) {
            A2[n] = -__expf(Alog[n*HIDDEN + d]) * LOG2E;
            Pv[n] = 1.f; Qv[n] = 0.f;
        }
        int s0 = c * CL;
        for (int i = 0; i < CL; ++i) {
            int r = b*SS + s0 + i;
            float dv = dt[r*HIDDEN + d];
            float xv = x[r*HIDDEN + d];
            float bm[NSTATE];
            *(float4*)&bm[0]  = *(const float4*)&xp[r*XPC + 0];
            *(float4*)&bm[4]  = *(const float4*)&xp[r*XPC + 4];
            *(float4*)&bm[8]  = *(const float4*)&xp[r*XPC + 8];
            *(float4*)&bm[12] = *(const float4*)&xp[r*XPC + 12];
            float bx = dv * xv;
            #pragma unroll
            for (int n = 0; n < NSTATE; ++n) {
                float a = exp2f(A2[n] * dv);
                Qv[n] = fmaf(a, Qv[n], bm[n] * bx);
                Pv[n] *= a;
            }
        }
        int base = b*(NSTATE*HIDDEN) + d;
        #pragma unroll
        for (int n = 0; n < NSTATE; ++n) {
            P[c*BND + base + n*HIDDEN] = Pv[n];
            Q[c*BND + base + n*HIDDEN] = Qv[n];
        }
    }
    gbar(bar + 2);

    // ================= phase 4: serial scan over chunks (blocks 0..127) =================
    if (bidx < BND / 256) {
        int bnd = bidx * 256 + t;
        float h = 0.f;
        for (int cb = 0; cb < CH / 8; ++cb) {
            float p[8], q[8];
            #pragma unroll
            for (int j = 0; j < 8; ++j) {
                int idx = (cb*8 + j)*BND + bnd;
                p[j] = P[idx]; q[j] = Q[idx];
            }
            #pragma unroll
            for (int j = 0; j < 8; ++j) {
                int idx = (cb*8 + j)*BND + bnd;
                P[idx] = h;                 // h_start for chunk
                h = fmaf(p[j], h, q[j]);
            }
        }
    }
    gbar(bar + 3);

    // ================= phase 5: re-run local scan from h_start, emit y =================
    {
        int dblk = bidx & 3;
        int b = (bidx >> 2) & 1;
        int c = bidx >> 3;
        int d = dblk * 256 + t;

        float A2[NSTATE], h[NSTATE];
        #pragma unroll
        for (int n = 0; n < NSTATE; ++n) {
            A2[n] = -__expf(Alog[n*HIDDEN + d]) * LOG2E;
            h[n] = P[c*BND + b*(NSTATE*HIDDEN) + n*HIDDEN + d];
        }
        int s0 = c * CL;
        for (int i = 0; i < CL; ++i) {
            int r = b*SS + s0 + i;
            float dv = dt[r*HIDDEN + d];
            float xv = x[r*HIDDEN + d];
            float bx = dv * xv;
            float bm[NSTATE], cm[NSTATE];
            *(float4*)&bm[0]  = *(const float4*)&xp[r*XPC + 0];
            *(float4*)&bm[4]  = *(const float4*)&xp[r*XPC + 4];
            *(float4*)&bm[8]  = *(const float4*)&xp[r*XPC + 8];
            *(float4*)&bm[12] = *(const float4*)&xp[r*XPC + 12];
            *(float4*)&cm[0]  = *(const float4*)&xp[r*XPC + 16];
            *(float4*)&cm[4]  = *(const float4*)&xp[r*XPC + 20];
            *(float4*)&cm[8]  = *(const float4*)&xp[r*XPC + 24];
            *(float4*)&cm[12] = *(const float4*)&xp[r*XPC + 28];
            float yv = 0.f;
            #pragma unroll
            for (int n = 0; n < NSTATE; ++n) {
                float a = exp2f(A2[n] * dv);
                h[n] = fmaf(a, h[n], bm[n] * bx);
                yv = fmaf(cm[n], h[n], yv);
            }
            y[r*HIDDEN + d] = yv;
        }
    }
}

extern "C" void kernel_launch(void* const* d_in, const int* in_sizes, int n_in,
                              void* d_out, int out_size, void* d_ws, size_t ws_size,
                              hipStream_t stream) {
    const float* x    = (const float*)d_in[0];
    const float* Wx   = (const float*)d_in[1];
    const float* Wdt  = (const float*)d_in[2];
    const float* bdt  = (const float*)d_in[3];
    const float* Alog = (const float*)d_in[4];
    float* y  = (float*)d_out;
    float* ws = (float*)d_ws;

    // workspace layout (~47.7 MB + 16 B)
    float* xp   = ws;                               // 393216
    float* dt   = xp + ROWS*XPC;                    // 4194304
    float* part = dt + ROWS*HIDDEN;                 // KSPL*ROWS*XPC = 3145728
    float* P    = part + (size_t)KSPL*ROWS*XPC;     // CH*BND = 2097152
    float* Q    = P + (size_t)CH*BND;               // 2097152
    int*   bar  = (int*)(Q + (size_t)CH*BND);       // 4 ints

    hipMemsetAsync(bar, 0, 4 * sizeof(int), stream);
    k_fused<<<NBLK, 256, 0, stream>>>(x, Wx, Wdt, bdt, Alog,
                                      part, xp, dt, P, Q, y, bar);
}

// Round 7
// 339.036 us; speedup vs baseline: 1.1964x; 1.1964x over previous
//
#include <hip/hip_runtime.h>
#include <math.h>

#define HIDDEN 1024
#define NSTATE 16
#define DTRANK 64
#define BB 2
#define SS 2048
#define ROWS (BB*SS)            // 4096
#define XPC 96                  // 2*STATE + DT_RANK
#define CH 64                   // chunks along S
#define CL 32                   // chunk length
#define BND (BB*NSTATE*HIDDEN)  // 32768
#define LOG2E 1.44269504088896f

#define RT 64                   // rows per xproj tile
#define KSPL 8                  // K splits in xproj
#define NBLK 512

// Manual grid barrier. Arrival: one device-scope atomicAdd per block (release).
// Poll: device-coherent PLAIN LOAD (no RMW, no exclusive ownership -> no
// cacheline ping-pong across 512 pollers). Counters zeroed before each launch.
__device__ __forceinline__ void gbar(int* c) {
    __syncthreads();
    if (threadIdx.x == 0) {
        __hip_atomic_fetch_add(c, 1, __ATOMIC_RELEASE, __HIP_MEMORY_SCOPE_AGENT);
        while (__hip_atomic_load(c, __ATOMIC_ACQUIRE, __HIP_MEMORY_SCOPE_AGENT) < NBLK)
            __builtin_amdgcn_s_sleep(8);
    }
    __syncthreads();
}

__global__ __launch_bounds__(256, 2)
void k_fused(const float* __restrict__ x, const float* __restrict__ W,
             const float* __restrict__ Wdt, const float* __restrict__ bdt,
             const float* __restrict__ Alog,
             float* __restrict__ part, float* __restrict__ xp,
             float* __restrict__ dt, float* __restrict__ P,
             float* __restrict__ Q, float* __restrict__ y,
             int* __restrict__ bar) {
    __shared__ float smem[96 * 36 + RT * 32];   // 22KB: wt + xs
    float* wt = smem;
    float* xs = smem + 96 * 36;

    int t = threadIdx.x;
    int bidx = blockIdx.x;

    // ================= phase 1: xproj partials (K-split GEMM) =================
    {
        int rt = bidx >> 3;
        int ks = bidx & 7;
        int r0 = rt * RT;
        int k0 = ks * 128;
        int cg_ = t & 15, rg = t >> 4;

        float acc[4][6];
        #pragma unroll
        for (int a = 0; a < 4; ++a)
            #pragma unroll
            for (int b = 0; b < 6; ++b) acc[a][b] = 0.f;

        for (int ch = 0; ch < 4; ++ch) {
            int kc = k0 + ch * 32;
            __syncthreads();
            #pragma unroll
            for (int m = 0; m < 2; ++m) {
                int e = t + m * 256;
                int row = e >> 3, kb = e & 7;
                float4 v = *(const float4*)&x[(r0 + row) * HIDDEN + kc + kb * 4];
                int kbp = kb ^ ((row >> 2) & 7);
                *(float4*)&xs[row * 32 + kbp * 4] = v;
            }
            #pragma unroll
            for (int m = 0; m < 3; ++m) {
                int f = t + m * 256;
                int kr = f / 24, cq = f % 24;
                float4 v = *(const float4*)&W[(kc + kr) * XPC + cq * 4];
                wt[(cq * 4 + 0) * 36 + kr] = v.x;
                wt[(cq * 4 + 1) * 36 + kr] = v.y;
                wt[(cq * 4 + 2) * 36 + kr] = v.z;
                wt[(cq * 4 + 3) * 36 + kr] = v.w;
            }
            __syncthreads();
            #pragma unroll
            for (int kg = 0; kg < 8; ++kg) {
                float4 wv[6], xv[4];
                #pragma unroll
                for (int j = 0; j < 6; ++j)
                    wv[j] = *(float4*)&wt[(cg_ + 16 * j) * 36 + kg * 4];
                #pragma unroll
                for (int rr = 0; rr < 4; ++rr) {
                    int row = rg * 4 + rr;
                    xv[rr] = *(float4*)&xs[row * 32 + ((kg ^ ((row >> 2) & 7)) * 4)];
                }
                #pragma unroll
                for (int rr = 0; rr < 4; ++rr)
                    #pragma unroll
                    for (int j = 0; j < 6; ++j) {
                        acc[rr][j] = fmaf(xv[rr].x, wv[j].x, acc[rr][j]);
                        acc[rr][j] = fmaf(xv[rr].y, wv[j].y, acc[rr][j]);
                        acc[rr][j] = fmaf(xv[rr].z, wv[j].z, acc[rr][j]);
                        acc[rr][j] = fmaf(xv[rr].w, wv[j].w, acc[rr][j]);
                    }
            }
        }
        #pragma unroll
        for (int rr = 0; rr < 4; ++rr)
            #pragma unroll
            for (int j = 0; j < 6; ++j)
                part[ks * (ROWS * XPC) + (r0 + rg * 4 + rr) * XPC + cg_ + 16 * j] = acc[rr][j];
    }
    gbar(bar + 0);

    // ================= phase 2: reduce partials -> xp, dt GEMM + softplus =================
    {
        float* xs2 = smem;                 // 8*64 floats
        int r0 = bidx * 8;
        #pragma unroll
        for (int m = 0; m < 3; ++m) {
            int o = t + m * 256;           // 0..767
            int row = o / 96, col = o % 96;
            float s = 0.f;
            #pragma unroll
            for (int p = 0; p < KSPL; ++p)
                s += part[p * (ROWS * XPC) + (r0 + row) * XPC + col];
            xp[(r0 + row) * XPC + col] = s;
            if (col >= 2 * NSTATE) xs2[row * 64 + (col - 2 * NSTATE)] = s;
        }
        __syncthreads();
        float4 acc[8];
        float4 b = *(const float4*)&bdt[t * 4];
        #pragma unroll
        for (int rr = 0; rr < 8; ++rr) acc[rr] = b;
        #pragma unroll 4
        for (int k = 0; k < DTRANK; ++k) {
            float4 w = *(const float4*)&Wdt[k * HIDDEN + t * 4];
            #pragma unroll
            for (int rr = 0; rr < 8; ++rr) {
                float s = xs2[rr * 64 + k];
                acc[rr].x = fmaf(s, w.x, acc[rr].x);
                acc[rr].y = fmaf(s, w.y, acc[rr].y);
                acc[rr].z = fmaf(s, w.z, acc[rr].z);
                acc[rr].w = fmaf(s, w.w, acc[rr].w);
            }
        }
        #pragma unroll
        for (int rr = 0; rr < 8; ++rr) {
            float4 a = acc[rr], o;
            o.x = fmaxf(a.x, 0.f) + log1pf(__expf(-fabsf(a.x)));
            o.y = fmaxf(a.y, 0.f) + log1pf(__expf(-fabsf(a.y)));
            o.z = fmaxf(a.z, 0.f) + log1pf(__expf(-fabsf(a.z)));
            o.w = fmaxf(a.w, 0.f) + log1pf(__expf(-fabsf(a.w)));
            *(float4*)&dt[(r0 + rr) * HIDDEN + t * 4] = o;
        }
    }
    gbar(bar + 1);

    // ================= phase 3: per-chunk P=prod(a), Q=local scan end =================
    {
        int dblk = bidx & 3;
        int b = (bidx >> 2) & 1;
        int c = bidx >> 3;
        int d = dblk * 256 + t;
        float A2[NSTATE], Pv[NSTATE], Qv[NSTATE];
        #pragma unroll
        for (int n = 0; n < NSTATE; ++n) {
            A2[n] = -__expf(Alog[n*HIDDEN + d]) * LOG2E;
            Pv[n] = 1.f; Qv[n] = 0.f;
        }
        int s0 = c * CL;
        for (int i = 0; i < CL; ++i) {
            int r = b*SS + s0 + i;
            float dv = dt[r*HIDDEN + d];
            float xv = x[r*HIDDEN + d];
            float bm[NSTATE];
            *(float4*)&bm[0]  = *(const float4*)&xp[r*XPC + 0];
            *(float4*)&bm[4]  = *(const float4*)&xp[r*XPC + 4];
            *(float4*)&bm[8]  = *(const float4*)&xp[r*XPC + 8];
            *(float4*)&bm[12] = *(const float4*)&xp[r*XPC + 12];
            float bx = dv * xv;
            #pragma unroll
            for (int n = 0; n < NSTATE; ++n) {
                float a = exp2f(A2[n] * dv);
                Qv[n] = fmaf(a, Qv[n], bm[n] * bx);
                Pv[n] *= a;
            }
        }
        int base = b*(NSTATE*HIDDEN) + d;
        #pragma unroll
        for (int n = 0; n < NSTATE; ++n) {
            P[c*BND + base + n*HIDDEN] = Pv[n];
            Q[c*BND + base + n*HIDDEN] = Qv[n];
        }
    }
    gbar(bar + 2);

    // ================= phase 4: serial scan over chunks (blocks 0..127) =================
    if (bidx < BND / 256) {
        int bnd = bidx * 256 + t;
        float h = 0.f;
        for (int cb = 0; cb < CH / 8; ++cb) {
            float p[8], q[8];
            #pragma unroll
            for (int j = 0; j < 8; ++j) {
                int idx = (cb*8 + j)*BND + bnd;
                p[j] = P[idx]; q[j] = Q[idx];
            }
            #pragma unroll
            for (int j = 0; j < 8; ++j) {
                int idx = (cb*8 + j)*BND + bnd;
                P[idx] = h;                 // h_start for chunk
                h = fmaf(p[j], h, q[j]);
            }
        }
    }
    gbar(bar + 3);

    // ================= phase 5: re-run local scan from h_start, emit y =================
    {
        int dblk = bidx & 3;
        int b = (bidx >> 2) & 1;
        int c = bidx >> 3;
        int d = dblk * 256 + t;

        float A2[NSTATE], h[NSTATE];
        #pragma unroll
        for (int n = 0; n < NSTATE; ++n) {
            A2[n] = -__expf(Alog[n*HIDDEN + d]) * LOG2E;
            h[n] = P[c*BND + b*(NSTATE*HIDDEN) + n*HIDDEN + d];
        }
        int s0 = c * CL;
        for (int i = 0; i < CL; ++i) {
            int r = b*SS + s0 + i;
            float dv = dt[r*HIDDEN + d];
            float xv = x[r*HIDDEN + d];
            float bx = dv * xv;
            float bm[NSTATE], cm[NSTATE];
            *(float4*)&bm[0]  = *(const float4*)&xp[r*XPC + 0];
            *(float4*)&bm[4]  = *(const float4*)&xp[r*XPC + 4];
            *(float4*)&bm[8]  = *(const float4*)&xp[r*XPC + 8];
            *(float4*)&bm[12] = *(const float4*)&xp[r*XPC + 12];
            *(float4*)&cm[0]  = *(const float4*)&xp[r*XPC + 16];
            *(float4*)&cm[4]  = *(const float4*)&xp[r*XPC + 20];
            *(float4*)&cm[8]  = *(const float4*)&xp[r*XPC + 24];
            *(float4*)&cm[12] = *(const float4*)&xp[r*XPC + 28];
            float yv = 0.f;
            #pragma unroll
            for (int n = 0; n < NSTATE; ++n) {
                float a = exp2f(A2[n] * dv);
                h[n] = fmaf(a, h[n], bm[n] * bx);
                yv = fmaf(cm[n], h[n], yv);
            }
            y[r*HIDDEN + d] = yv;
        }
    }
}

extern "C" void kernel_launch(void* const* d_in, const int* in_sizes, int n_in,
                              void* d_out, int out_size, void* d_ws, size_t ws_size,
                              hipStream_t stream) {
    const float* x    = (const float*)d_in[0];
    const float* Wx   = (const float*)d_in[1];
    const float* Wdt  = (const float*)d_in[2];
    const float* bdt  = (const float*)d_in[3];
    const float* Alog = (const float*)d_in[4];
    float* y  = (float*)d_out;
    float* ws = (float*)d_ws;

    // workspace layout (~47.7 MB + 16 B)
    float* xp   = ws;                               // 393216
    float* dt   = xp + ROWS*XPC;                    // 4194304
    float* part = dt + ROWS*HIDDEN;                 // KSPL*ROWS*XPC = 3145728
    float* P    = part + (size_t)KSPL*ROWS*XPC;     // CH*BND = 2097152
    float* Q    = P + (size_t)CH*BND;               // 2097152
    int*   bar  = (int*)(Q + (size_t)CH*BND);       // 4 ints

    hipMemsetAsync(bar, 0, 4 * sizeof(int), stream);
    k_fused<<<NBLK, 256, 0, stream>>>(x, Wx, Wdt, bdt, Alog,
                                      part, xp, dt, P, Q, y, bar);
}

// Round 8
// 112.384 us; speedup vs baseline: 3.6093x; 3.0168x over previous
//
#include <hip/hip_runtime.h>
#include <math.h>

#define HIDDEN 1024
#define NSTATE 16
#define DTRANK 64
#define BB 2
#define SS 2048
#define ROWS (BB*SS)            // 4096
#define XPC 96                  // 2*STATE + DT_RANK
#define CH 128                  // chunks along S  (occupancy test: 64 -> 128)
#define CL 16                   // chunk length
#define BND (BB*NSTATE*HIDDEN)  // 32768
#define LOG2E 1.44269504088896f

#define RT 64                   // rows per k1 block
#define KSPL 8                  // K splits in k1

// ---------------- K1: partial xp = x @ W_xproj, K-split ----------------
// grid 512 = 64 row-tiles x 8 k-splits; block 256 (16 col-groups x 16 row-groups)
__global__ __launch_bounds__(256) void k_xproj2(const float* __restrict__ x,
                                                const float* __restrict__ W,
                                                float* __restrict__ part) {
    __shared__ float xs[RT * 32];      // [row][kb^swz] float4 blocks, 8KB
    __shared__ float wt[96 * 36];      // transposed W [c][k], stride 36, 13.5KB
    int t  = threadIdx.x;
    int rt = blockIdx.x >> 3;
    int ks = blockIdx.x & 7;
    int r0 = rt * RT;
    int k0 = ks * 128;
    int cg = t & 15, rg = t >> 4;

    float acc[4][6];
    #pragma unroll
    for (int a = 0; a < 4; ++a)
        #pragma unroll
        for (int b = 0; b < 6; ++b) acc[a][b] = 0.f;

    for (int ch = 0; ch < 4; ++ch) {
        int kc = k0 + ch * 32;
        __syncthreads();
        #pragma unroll
        for (int m = 0; m < 2; ++m) {
            int e = t + m * 256;
            int row = e >> 3, kb = e & 7;
            float4 v = *(const float4*)&x[(r0 + row) * HIDDEN + kc + kb * 4];
            int kbp = kb ^ ((row >> 2) & 7);
            *(float4*)&xs[row * 32 + kbp * 4] = v;
        }
        #pragma unroll
        for (int m = 0; m < 3; ++m) {
            int f = t + m * 256;
            int kr = f / 24, cq = f % 24;
            float4 v = *(const float4*)&W[(kc + kr) * XPC + cq * 4];
            wt[(cq * 4 + 0) * 36 + kr] = v.x;
            wt[(cq * 4 + 1) * 36 + kr] = v.y;
            wt[(cq * 4 + 2) * 36 + kr] = v.z;
            wt[(cq * 4 + 3) * 36 + kr] = v.w;
        }
        __syncthreads();
        #pragma unroll
        for (int kg = 0; kg < 8; ++kg) {
            float4 wv[6], xv[4];
            #pragma unroll
            for (int j = 0; j < 6; ++j)
                wv[j] = *(float4*)&wt[(cg + 16 * j) * 36 + kg * 4];
            #pragma unroll
            for (int rr = 0; rr < 4; ++rr) {
                int row = rg * 4 + rr;
                xv[rr] = *(float4*)&xs[row * 32 + ((kg ^ ((row >> 2) & 7)) * 4)];
            }
            #pragma unroll
            for (int rr = 0; rr < 4; ++rr)
                #pragma unroll
                for (int j = 0; j < 6; ++j) {
                    acc[rr][j] = fmaf(xv[rr].x, wv[j].x, acc[rr][j]);
                    acc[rr][j] = fmaf(xv[rr].y, wv[j].y, acc[rr][j]);
                    acc[rr][j] = fmaf(xv[rr].z, wv[j].z, acc[rr][j]);
                    acc[rr][j] = fmaf(xv[rr].w, wv[j].w, acc[rr][j]);
                }
        }
    }
    #pragma unroll
    for (int rr = 0; rr < 4; ++rr)
        #pragma unroll
        for (int j = 0; j < 6; ++j)
            part[ks * (ROWS * XPC) + (r0 + rg * 4 + rr) * XPC + cg + 16 * j] = acc[rr][j];
}

// ---------------- K2: fused reduce(part)->xp  +  dt = softplus(xp_dt @ W_dt + b) ----------------
__global__ void k_rdt(const float* __restrict__ part, const float* __restrict__ Wdt,
                      const float* __restrict__ bdt, float* __restrict__ xp,
                      float* __restrict__ dt) {
    __shared__ float xs[8 * 64];
    int t = threadIdx.x;
    int r0 = blockIdx.x * 8;
    #pragma unroll
    for (int m = 0; m < 3; ++m) {
        int o = t + m * 256;              // 0..767
        int row = o / 96, col = o % 96;
        float s = 0.f;
        #pragma unroll
        for (int p = 0; p < KSPL; ++p)
            s += part[p * (ROWS * XPC) + (r0 + row) * XPC + col];
        xp[(r0 + row) * XPC + col] = s;
        if (col >= 2 * NSTATE) xs[row * 64 + (col - 2 * NSTATE)] = s;
    }
    __syncthreads();
    float4 acc[8];
    float4 b = *(const float4*)&bdt[t * 4];
    #pragma unroll
    for (int rr = 0; rr < 8; ++rr) acc[rr] = b;
    #pragma unroll 4
    for (int k = 0; k < DTRANK; ++k) {
        float4 w = *(const float4*)&Wdt[k * HIDDEN + t * 4];
        #pragma unroll
        for (int rr = 0; rr < 8; ++rr) {
            float s = xs[rr * 64 + k];
            acc[rr].x = fmaf(s, w.x, acc[rr].x);
            acc[rr].y = fmaf(s, w.y, acc[rr].y);
            acc[rr].z = fmaf(s, w.z, acc[rr].z);
            acc[rr].w = fmaf(s, w.w, acc[rr].w);
        }
    }
    #pragma unroll
    for (int rr = 0; rr < 8; ++rr) {
        float4 a = acc[rr], o;
        o.x = fmaxf(a.x, 0.f) + log1pf(__expf(-fabsf(a.x)));
        o.y = fmaxf(a.y, 0.f) + log1pf(__expf(-fabsf(a.y)));
        o.z = fmaxf(a.z, 0.f) + log1pf(__expf(-fabsf(a.z)));
        o.w = fmaxf(a.w, 0.f) + log1pf(__expf(-fabsf(a.w)));
        *(float4*)&dt[(r0 + rr) * HIDDEN + t * 4] = o;
    }
}

// ---------------- K3 (pass 1): thread owns (c,b,d), all 16 states in regs ----------------
// grid = CH*BB*4 = 1024 blocks -> 16 waves/CU
__global__ __launch_bounds__(256, 4)
void k_pass1(const float* __restrict__ x, const float* __restrict__ dt,
             const float* __restrict__ xp, const float* __restrict__ Alog,
             float* __restrict__ P, float* __restrict__ Q) {
    int bid = blockIdx.x;
    int dblk = bid & 3;
    int b = (bid >> 2) & 1;
    int c = bid >> 3;
    int d = dblk * 256 + threadIdx.x;
    float A2[NSTATE], Pv[NSTATE], Qv[NSTATE];
    #pragma unroll
    for (int n = 0; n < NSTATE; ++n) {
        A2[n] = -__expf(Alog[n*HIDDEN + d]) * LOG2E;
        Pv[n] = 1.f; Qv[n] = 0.f;
    }
    int s0 = c * CL;
    #pragma unroll 4
    for (int i = 0; i < CL; ++i) {
        int r = b*SS + s0 + i;
        float dv = dt[r*HIDDEN + d];
        float xv = x[r*HIDDEN + d];
        float bm[NSTATE];
        *(float4*)&bm[0]  = *(const float4*)&xp[r*XPC + 0];
        *(float4*)&bm[4]  = *(const float4*)&xp[r*XPC + 4];
        *(float4*)&bm[8]  = *(const float4*)&xp[r*XPC + 8];
        *(float4*)&bm[12] = *(const float4*)&xp[r*XPC + 12];
        float bx = dv * xv;
        #pragma unroll
        for (int n = 0; n < NSTATE; ++n) {
            float a = exp2f(A2[n] * dv);
            Qv[n] = fmaf(a, Qv[n], bm[n] * bx);
            Pv[n] *= a;
        }
    }
    int base = b*(NSTATE*HIDDEN) + d;
    #pragma unroll
    for (int n = 0; n < NSTATE; ++n) {
        P[c*BND + base + n*HIDDEN] = Pv[n];
        Q[c*BND + base + n*HIDDEN] = Qv[n];
    }
}

// ---------------- K4 (pass 2): serial scan over chunks, 16-deep batched loads ----------------
__global__ void k_pass2(float* __restrict__ P, const float* __restrict__ Q) {
    int bnd = blockIdx.x * 256 + threadIdx.x;   // < 32768
    float h = 0.f;
    for (int cb = 0; cb < CH / 16; ++cb) {
        float p[16], q[16];
        #pragma unroll
        for (int j = 0; j < 16; ++j) {
            int idx = (cb*16 + j)*BND + bnd;
            p[j] = P[idx]; q[j] = Q[idx];
        }
        #pragma unroll
        for (int j = 0; j < 16; ++j) {
            int idx = (cb*16 + j)*BND + bnd;
            P[idx] = h;                 // h_start for chunk
            h = fmaf(p[j], h, q[j]);
        }
    }
}

// ---------------- K5 (pass 3): re-run local scan from h_start, emit y ----------------
// grid = CH*BB*4 = 1024 blocks -> 16 waves/CU
__global__ __launch_bounds__(256, 4)
void k_pass3(const float* __restrict__ x, const float* __restrict__ dt,
             const float* __restrict__ xp, const float* __restrict__ Alog,
             const float* __restrict__ Hs, float* __restrict__ y) {
    int bid = blockIdx.x;
    int dblk = bid & 3;
    int b = (bid >> 2) & 1;
    int c = bid >> 3;
    int d = dblk * 256 + threadIdx.x;

    float A2[NSTATE], h[NSTATE];
    #pragma unroll
    for (int n = 0; n < NSTATE; ++n) {
        A2[n] = -__expf(Alog[n*HIDDEN + d]) * LOG2E;
        h[n] = Hs[c*BND + b*(NSTATE*HIDDEN) + n*HIDDEN + d];
    }
    int s0 = c * CL;
    #pragma unroll 2
    for (int i = 0; i < CL; ++i) {
        int r = b*SS + s0 + i;
        float dv = dt[r*HIDDEN + d];
        float xv = x[r*HIDDEN + d];
        float bx = dv * xv;
        float bm[NSTATE], cm[NSTATE];
        *(float4*)&bm[0]  = *(const float4*)&xp[r*XPC + 0];
        *(float4*)&bm[4]  = *(const float4*)&xp[r*XPC + 4];
        *(float4*)&bm[8]  = *(const float4*)&xp[r*XPC + 8];
        *(float4*)&bm[12] = *(const float4*)&xp[r*XPC + 12];
        *(float4*)&cm[0]  = *(const float4*)&xp[r*XPC + 16];
        *(float4*)&cm[4]  = *(const float4*)&xp[r*XPC + 20];
        *(float4*)&cm[8]  = *(const float4*)&xp[r*XPC + 24];
        *(float4*)&cm[12] = *(const float4*)&xp[r*XPC + 28];
        float yv = 0.f;
        #pragma unroll
        for (int n = 0; n < NSTATE; ++n) {
            float a = exp2f(A2[n] * dv);
            h[n] = fmaf(a, h[n], bm[n] * bx);
            yv = fmaf(cm[n], h[n], yv);
        }
        y[r*HIDDEN + d] = yv;
    }
}

extern "C" void kernel_launch(void* const* d_in, const int* in_sizes, int n_in,
                              void* d_out, int out_size, void* d_ws, size_t ws_size,
                              hipStream_t stream) {
    const float* x    = (const float*)d_in[0];
    const float* Wx   = (const float*)d_in[1];
    const float* Wdt  = (const float*)d_in[2];
    const float* bdt  = (const float*)d_in[3];
    const float* Alog = (const float*)d_in[4];
    float* y  = (float*)d_out;
    float* ws = (float*)d_ws;

    float* xp   = ws;                               // 393216 floats
    float* dt   = xp + ROWS*XPC;                    // 4194304 floats
    float* part = dt + ROWS*HIDDEN;                 // KSPL*ROWS*XPC = 3145728
    float* P    = part + (size_t)KSPL*ROWS*XPC;     // CH*BND = 4194304
    float* Q    = P + (size_t)CH*BND;               // 4194304
    // total ws use: ~64 MB

    k_xproj2<<<(ROWS/RT)*KSPL, 256, 0, stream>>>(x, Wx, part);
    k_rdt<<<ROWS/8, 256, 0, stream>>>(part, Wdt, bdt, xp, dt);
    k_pass1<<<CH*BB*4, 256, 0, stream>>>(x, dt, xp, Alog, P, Q);
    k_pass2<<<BND/256, 256, 0, stream>>>(P, Q);
    k_pass3<<<CH*BB*4, 256, 0, stream>>>(x, dt, xp, Alog, P, y);
}